// Round 1
// baseline (191.292 us; speedup 1.0000x reference)
//
#include <hip/hip_runtime.h>
#include <math.h>

#define BB 4
#define TT 4096
#define CC 1024
#define HS 64
#define WIN 512
#define NROW (BB*TT)   // 16384 rows total

// ---------------- Projection: [q|k|v] = x @ [wq|wk|wv] ----------------
// tile: 32 rows x 192 cols, 256 threads, thread tile 2 rows x 12 cols
#define P_ROWS 32
#define P_KC 32

__global__ __launch_bounds__(256) void proj_kernel(
    const float* __restrict__ x,
    const float* __restrict__ wq,
    const float* __restrict__ wk,
    const float* __restrict__ wv,
    float* __restrict__ qo, float* __restrict__ ko, float* __restrict__ vo)
{
  __shared__ float xs[P_KC][P_ROWS + 4];   // x tile transposed: [k][row]
  __shared__ float wls[P_KC][192 + 4];     // weights: [k][col], cols = q|k|v

  const int tid = threadIdx.x;
  const int row0 = blockIdx.x * P_ROWS;
  const int tr = tid >> 4;   // 0..15 -> rows tr*2, tr*2+1
  const int tc = tid & 15;   // 0..15 -> cols tc*12 .. +11

  float acc[2][12];
  #pragma unroll
  for (int r = 0; r < 2; ++r)
    #pragma unroll
    for (int c = 0; c < 12; ++c) acc[r][c] = 0.f;

  for (int kc = 0; kc < CC; kc += P_KC) {
    __syncthreads();
    {
      // stage x tile: 32 rows x 32 k = 256 float4, one per thread
      int r  = tid >> 3;        // 0..31
      int c4 = tid & 7;         // 0..7 (8 float4 per row)
      float4 xv = *(const float4*)&x[(size_t)(row0 + r)*CC + kc + c4*4];
      xs[c4*4+0][r] = xv.x;
      xs[c4*4+1][r] = xv.y;
      xs[c4*4+2][r] = xv.z;
      xs[c4*4+3][r] = xv.w;
      // stage w tile: 32 k x 192 cols = 1536 float4, 6 per thread
      #pragma unroll
      for (int i = 0; i < 6; ++i) {
        int slot = tid + i*256;
        int kk  = slot / 48;        // 0..31
        int c4w = slot % 48;        // 48 float4 per k-row
        int m   = c4w >> 4;         // which matrix (16 float4 = 64 cols each)
        int cc4 = (c4w & 15) * 4;   // col within matrix
        const float* wsrc = (m == 0) ? wq : (m == 1) ? wk : wv;
        float4 wv4 = *(const float4*)&wsrc[(size_t)(kc + kk)*HS + cc4];
        *(float4*)&wls[kk][m*64 + cc4] = wv4;
      }
    }
    __syncthreads();
    #pragma unroll
    for (int kk = 0; kk < P_KC; ++kk) {
      float2 a = *(const float2*)&xs[kk][tr*2];
      float b[12];
      *(float4*)&b[0] = *(const float4*)&wls[kk][tc*12];
      *(float4*)&b[4] = *(const float4*)&wls[kk][tc*12 + 4];
      *(float4*)&b[8] = *(const float4*)&wls[kk][tc*12 + 8];
      #pragma unroll
      for (int c = 0; c < 12; ++c) {
        acc[0][c] += a.x * b[c];
        acc[1][c] += a.y * b[c];
      }
    }
  }
  // store
  #pragma unroll
  for (int r = 0; r < 2; ++r) {
    int row = row0 + tr*2 + r;
    #pragma unroll
    for (int c = 0; c < 12; ++c) {
      int col = tc*12 + c;
      int m   = col >> 6;
      int cc2 = col & 63;
      float* dst = (m == 0) ? qo : (m == 1) ? ko : vo;
      dst[(size_t)row*HS + cc2] = acc[r][c];
    }
  }
}

// ---------------- Sliding-window flash attention ----------------
// One block per (batch, 64-query tile). 256 threads: 4 threads per query.
// thread (qi, sub): QK over keys [sub*16, sub*16+16); PV over dims [sub*16, +16)
__global__ __launch_bounds__(256) void attn_kernel(
    const float* __restrict__ qm, const float* __restrict__ km,
    const float* __restrict__ vm, float* __restrict__ out)
{
  __shared__ float qs[64][68];
  __shared__ float ks[64][68];   // column-XOR-swizzled by (row>>4)&3
  __shared__ float vs[64][68];
  __shared__ float ps[64][65];

  const int tid = threadIdx.x;
  const int b   = blockIdx.x >> 6;
  const int qt  = blockIdx.x & 63;
  const int t0  = qt * 64;
  const size_t base = (size_t)b * TT * HS;

  // load q tile (64x64 f32)
  #pragma unroll
  for (int i = 0; i < 4; ++i) {
    int slot = tid + i*256;
    int r  = slot >> 4;
    int c4 = (slot & 15) * 4;
    *(float4*)&qs[r][c4] = *(const float4*)&qm[base + (size_t)(t0 + r)*HS + c4];
  }

  const int qi  = tid >> 2;   // 0..63 query within tile
  const int sub = tid & 3;    // 0..3
  const int tg  = t0 + qi;    // global query position

  float m_run = -INFINITY;
  float l_run = 0.f;
  float o[16];
  #pragma unroll
  for (int d = 0; d < 16; ++d) o[d] = 0.f;

  int s_lo = t0 - WIN; if (s_lo < 0) s_lo = 0;

  for (int sc = s_lo; sc < t0 + 64; sc += 64) {
    __syncthreads();   // previous PV done reading vs/ps
    // stage k (swizzled) and v chunk
    #pragma unroll
    for (int i = 0; i < 4; ++i) {
      int slot = tid + i*256;
      int r  = slot >> 4;
      int c4 = slot & 15;
      float4 kv = *(const float4*)&km[base + (size_t)(sc + r)*HS + c4*4];
      float4 vv = *(const float4*)&vm[base + (size_t)(sc + r)*HS + c4*4];
      *(float4*)&ks[r][(c4 ^ ((r >> 4) & 3)) * 4] = kv;
      *(float4*)&vs[r][c4*4] = vv;
    }
    __syncthreads();

    // ---- QK^T: 16 scores per thread ----
    float s[16];
    #pragma unroll
    for (int j = 0; j < 16; ++j) s[j] = 0.f;
    #pragma unroll
    for (int d4 = 0; d4 < 16; ++d4) {
      float4 qv = *(const float4*)&qs[qi][d4*4];
      #pragma unroll
      for (int j = 0; j < 16; ++j) {
        float4 kv = *(const float4*)&ks[sub*16 + j][((d4 ^ sub) & 15) * 4];
        s[j] += qv.x*kv.x + qv.y*kv.y + qv.z*kv.z + qv.w*kv.w;
      }
    }

    // ---- mask + scale + online softmax ----
    const float scale = 0.125f;   // 1/sqrt(64)
    float mc = -INFINITY;
    #pragma unroll
    for (int j = 0; j < 16; ++j) {
      int sg = sc + sub*16 + j;
      int diff = tg - sg;
      s[j] = (diff >= 0 && diff < WIN) ? s[j]*scale : -INFINITY;
      mc = fmaxf(mc, s[j]);
    }
    mc = fmaxf(mc, __shfl_xor(mc, 1));
    mc = fmaxf(mc, __shfl_xor(mc, 2));
    float m_new = fmaxf(m_run, mc);
    float factor = 1.f;
    float lsum = 0.f;
    if (m_new == -INFINITY) {
      // no valid key seen yet for this query: p = 0, state unchanged
      #pragma unroll
      for (int j = 0; j < 16; ++j) ps[qi][sub*16 + j] = 0.f;
    } else {
      factor = __expf(m_run - m_new);   // m_run=-inf -> 0
      #pragma unroll
      for (int j = 0; j < 16; ++j) {
        float p = __expf(s[j] - m_new); // s=-inf -> 0
        ps[qi][sub*16 + j] = p;
        lsum += p;
      }
    }
    lsum += __shfl_xor(lsum, 1);
    lsum += __shfl_xor(lsum, 2);
    l_run = l_run * factor + lsum;
    m_run = m_new;
    #pragma unroll
    for (int d = 0; d < 16; ++d) o[d] *= factor;
    __syncthreads();   // ps visible to all

    // ---- PV: o[dims sub*16..+15] += sum_kk p[qi][kk] * v[kk][dims] ----
    #pragma unroll 4
    for (int kk = 0; kk < 64; ++kk) {
      float p = ps[qi][kk];
      const float* vrow = &vs[kk][sub*16];
      float4 v0 = *(const float4*)&vrow[0];
      float4 v1 = *(const float4*)&vrow[4];
      float4 v2 = *(const float4*)&vrow[8];
      float4 v3 = *(const float4*)&vrow[12];
      o[0]  += p*v0.x; o[1]  += p*v0.y; o[2]  += p*v0.z; o[3]  += p*v0.w;
      o[4]  += p*v1.x; o[5]  += p*v1.y; o[6]  += p*v1.z; o[7]  += p*v1.w;
      o[8]  += p*v2.x; o[9]  += p*v2.y; o[10] += p*v2.z; o[11] += p*v2.w;
      o[12] += p*v3.x; o[13] += p*v3.y; o[14] += p*v3.z; o[15] += p*v3.w;
    }
  }

  float inv = 1.f / l_run;
  size_t obase = base + (size_t)tg*HS + sub*16;
  float4 w0 = make_float4(o[0]*inv,  o[1]*inv,  o[2]*inv,  o[3]*inv);
  float4 w1 = make_float4(o[4]*inv,  o[5]*inv,  o[6]*inv,  o[7]*inv);
  float4 w2 = make_float4(o[8]*inv,  o[9]*inv,  o[10]*inv, o[11]*inv);
  float4 w3 = make_float4(o[12]*inv, o[13]*inv, o[14]*inv, o[15]*inv);
  *(float4*)&out[obase + 0]  = w0;
  *(float4*)&out[obase + 4]  = w1;
  *(float4*)&out[obase + 8]  = w2;
  *(float4*)&out[obase + 12] = w3;
}

extern "C" void kernel_launch(void* const* d_in, const int* in_sizes, int n_in,
                              void* d_out, int out_size, void* d_ws, size_t ws_size,
                              hipStream_t stream) {
  // setup_inputs dict order: x, w_key, w_query, w_value
  const float* x  = (const float*)d_in[0];
  const float* wk = (const float*)d_in[1];
  const float* wq = (const float*)d_in[2];
  const float* wv = (const float*)d_in[3];
  float* out = (float*)d_out;

  // workspace: q, k, v projections (f32), 3 * 16384*64 floats = 12.6 MB
  float* q = (float*)d_ws;
  float* k = q + (size_t)NROW * HS;
  float* v = k + (size_t)NROW * HS;

  proj_kernel<<<NROW / P_ROWS, 256, 0, stream>>>(x, wq, wk, wv, q, k, v);
  attn_kernel<<<BB * (TT / 64), 256, 0, stream>>>(q, k, v, out);
}

// Round 2
// 132.838 us; speedup vs baseline: 1.4400x; 1.4400x over previous
//
#include <hip/hip_runtime.h>
#include <math.h>

#define BB 4
#define TT 4096
#define CC 1024
#define HS 64
#define WIN 512
#define NROW (BB*TT)

typedef float f32x4 __attribute__((ext_vector_type(4)));
typedef short bf16x8 __attribute__((ext_vector_type(8)));

#define MFMA16(a, b, c) __builtin_amdgcn_mfma_f32_16x16x32_bf16((a), (b), (c), 0, 0, 0)

__device__ inline unsigned short f2b(float f) {
  union { float f; unsigned u; } v; v.f = f;
  unsigned r = v.u + 0x7FFFu + ((v.u >> 16) & 1u);   // round-nearest-even
  return (unsigned short)(r >> 16);
}

// ---------------- pack W into MFMA B-fragment order (bf16) ----------------
// wp flat index: ((kt*12 + nb)*64 + lane)*8 + j
// holds W[k = kt*32 + (lane>>4)*8 + j][n = nb*16 + (lane&15)],
// n: 0..63 = w_query, 64..127 = w_key, 128..191 = w_value
__global__ __launch_bounds__(256) void pack_w_kernel(
    const float* __restrict__ wq, const float* __restrict__ wk,
    const float* __restrict__ wv, unsigned short* __restrict__ wp)
{
  int t = blockIdx.x * 256 + threadIdx.x;   // 49152 threads
  int kg = t / 48;                          // 0..1023  (k index)
  int nq = t % 48;                          // 4-col group
  int n0 = nq * 4;
  int m  = n0 >> 6;
  int c  = n0 & 63;
  const float* w = (m == 0) ? wq : (m == 1) ? wk : wv;
  float4 v = *(const float4*)&w[(size_t)kg * HS + c];
  int kt = kg >> 5;
  int hi = (kg >> 3) & 3;
  int j  = kg & 7;
  float vals[4] = {v.x, v.y, v.z, v.w};
  #pragma unroll
  for (int i = 0; i < 4; ++i) {
    int n  = n0 + i;
    int nb = n >> 4;
    int rl = n & 15;
    int lane = hi * 16 + rl;
    wp[((size_t)(kt * 12 + nb) * 64 + lane) * 8 + j] = f2b(vals[i]);
  }
}

// ---------------- Projection via MFMA: [q|k|v] = x @ W ----------------
// grid 256 blocks x 256 threads (4 waves). Wave = 16 rows x 192 cols.
// Outputs: q_ws,k_ws row-major bf16 [row][64]; vt_ws transposed per 64-row
// chunk: [chunk][d][key] bf16.
__global__ __launch_bounds__(256) void proj_mfma_kernel(
    const float* __restrict__ x, const unsigned short* __restrict__ wp,
    unsigned short* __restrict__ q_ws, unsigned short* __restrict__ k_ws,
    unsigned short* __restrict__ vt_ws)
{
  const int tid = threadIdx.x;
  const int l   = tid & 63;
  const int wid = tid >> 6;
  const int r0  = blockIdx.x * 64 + wid * 16;
  const int rl  = l & 15;
  const int hi  = l >> 4;

  f32x4 acc[12];
  #pragma unroll
  for (int i = 0; i < 12; ++i) acc[i] = (f32x4){0.f, 0.f, 0.f, 0.f};

  const float* xrow = x + (size_t)(r0 + rl) * CC + hi * 8;

  for (int kt = 0; kt < 32; ++kt) {
    float4 a0 = *(const float4*)(xrow + kt * 32);
    float4 a1 = *(const float4*)(xrow + kt * 32 + 4);
    bf16x8 af;
    af[0] = (short)f2b(a0.x); af[1] = (short)f2b(a0.y);
    af[2] = (short)f2b(a0.z); af[3] = (short)f2b(a0.w);
    af[4] = (short)f2b(a1.x); af[5] = (short)f2b(a1.y);
    af[6] = (short)f2b(a1.z); af[7] = (short)f2b(a1.w);
    const unsigned short* wpk = wp + (size_t)kt * 6144 + l * 8;
    #pragma unroll
    for (int nb = 0; nb < 12; ++nb) {
      bf16x8 bf = *(const bf16x8*)(wpk + nb * 512);
      acc[nb] = MFMA16(af, bf, acc[nb]);
    }
  }

  // q (cols 0..63) and k (cols 64..127): row-major scalar bf16 stores
  #pragma unroll
  for (int nb = 0; nb < 8; ++nb) {
    unsigned short* dst = (nb < 4) ? q_ws : k_ws;
    int c = (nb & 3) * 16 + rl;
    #pragma unroll
    for (int r = 0; r < 4; ++r) {
      int row = r0 + hi * 4 + r;
      dst[(size_t)row * HS + c] = f2b(acc[nb][r]);
    }
  }
  // v (cols 128..191): transposed per 64-chunk, packed 4-key stores
  int ch   = r0 >> 6;
  int key0 = (r0 & 63) + hi * 4;
  #pragma unroll
  for (int nb = 8; nb < 12; ++nb) {
    int d = (nb - 8) * 16 + rl;
    unsigned u0 = (unsigned)f2b(acc[nb][0]) | ((unsigned)f2b(acc[nb][1]) << 16);
    unsigned u1 = (unsigned)f2b(acc[nb][2]) | ((unsigned)f2b(acc[nb][3]) << 16);
    uint2 uu; uu.x = u0; uu.y = u1;
    *(uint2*)(vt_ws + (size_t)ch * 4096 + d * 64 + key0) = uu;
  }
}

// ---------------- Sliding-window flash attention via MFMA ----------------
// grid 256 blocks (b, 64-q tile) x 256 threads (4 waves, 16 q-rows each).
// Swapped QK^T (S^T = K @ Q^T) -> softmax lane-local; P via wave-private LDS;
// PV with V^T staged swizzled.
__global__ __launch_bounds__(256) void attn_mfma_kernel(
    const unsigned short* __restrict__ q_ws, const unsigned short* __restrict__ k_ws,
    const unsigned short* __restrict__ vt_ws, float* __restrict__ out)
{
  __shared__ uint4 smem4[1600];                 // 25600 B
  unsigned char* smem = (unsigned char*)smem4;  // K:[0,8K) Vt:[8K,16K) P:16K+

  const int tid = threadIdx.x;
  const int l   = tid & 63;
  const int wid = tid >> 6;
  const int rl  = l & 15;
  const int hi  = l >> 4;
  const int b   = blockIdx.x >> 6;
  const int qt  = blockIdx.x & 63;
  const int t0  = qt * 64;
  const int t0w = t0 + wid * 16;

  // Q B-fragments (held in registers): lane = q row t0w+rl, d = hi*8+j (+32)
  const unsigned short* qrow = q_ws + (size_t)(b * TT + t0w + rl) * HS;
  bf16x8 qb0 = *(const bf16x8*)(qrow + hi * 8);
  bf16x8 qb1 = *(const bf16x8*)(qrow + 32 + hi * 8);

  f32x4 oacc[4];
  #pragma unroll
  for (int i = 0; i < 4; ++i) oacc[i] = (f32x4){0.f, 0.f, 0.f, 0.f};
  float m_run = -INFINITY, l_run = 0.f;

  int s_lo = t0 - WIN; if (s_lo < 0) s_lo = 0;
  unsigned char* pbase = smem + 16384 + wid * 2304 + rl * 144;

  for (int sc = s_lo; sc < t0 + 64; sc += 64) {
    __syncthreads();
    // ---- stage K and Vt chunk (64x64 bf16 each), XOR-swizzled rows ----
    {
      const unsigned short* kg = k_ws + (size_t)(b * TT + sc) * HS;
      const unsigned short* vg = vt_ws + (size_t)((b * TT + sc) >> 6) * 4096;
      #pragma unroll
      for (int i = 0; i < 2; ++i) {
        int idx = tid + i * 256;
        int row = idx >> 3;
        int c16 = idx & 7;
        uint4 kv = *(const uint4*)(kg + row * 64 + c16 * 8);
        uint4 vv = *(const uint4*)(vg + row * 64 + c16 * 8);
        *(uint4*)(smem + row * 128 + ((c16 ^ (row & 7)) * 16)) = kv;
        *(uint4*)(smem + 8192 + row * 128 + ((c16 ^ (row & 7)) * 16)) = vv;
      }
    }
    __syncthreads();

    // ---- S^T = K @ Q^T : 4 key-block fragments ----
    f32x4 sacc[4];
    #pragma unroll
    for (int i = 0; i < 4; ++i) sacc[i] = (f32x4){0.f, 0.f, 0.f, 0.f};
    #pragma unroll
    for (int kb = 0; kb < 4; ++kb) {
      int row = kb * 16 + rl;
      unsigned char* kr = smem + row * 128;
      bf16x8 k0 = *(const bf16x8*)(kr + (((hi) ^ (row & 7)) * 16));
      bf16x8 k1 = *(const bf16x8*)(kr + (((4 + hi) ^ (row & 7)) * 16));
      sacc[kb] = MFMA16(k0, qb0, sacc[kb]);
      sacc[kb] = MFMA16(k1, qb1, sacc[kb]);
    }

    // ---- mask + scale + online softmax (lane owns one q = t0w+rl) ----
    const int tg = t0w + rl;
    float p[16];
    float tm = -INFINITY;
    bool full = (sc + 63 <= t0w) && (sc >= t0w - 496);
    #pragma unroll
    for (int kb = 0; kb < 4; ++kb)
      #pragma unroll
      for (int r = 0; r < 4; ++r) {
        float v = sacc[kb][r] * 0.125f;
        if (!full) {
          int key = sc + kb * 16 + hi * 4 + r;
          int diff = tg - key;
          v = (diff >= 0 && diff < WIN) ? v : -INFINITY;
        }
        p[kb * 4 + r] = v;
        tm = fmaxf(tm, v);
      }
    tm = fmaxf(tm, __shfl_xor(tm, 16));
    tm = fmaxf(tm, __shfl_xor(tm, 32));
    float m_new = fmaxf(m_run, tm);
    float fac  = (m_new == -INFINITY) ? 1.f : __expf(m_run - m_new);
    float msub = (m_new == -INFINITY) ? 0.f : m_new;
    float lsum = 0.f;
    #pragma unroll
    for (int i = 0; i < 16; ++i) { p[i] = __expf(p[i] - msub); lsum += p[i]; }
    lsum += __shfl_xor(lsum, 16);
    lsum += __shfl_xor(lsum, 32);
    l_run = l_run * fac + lsum;
    m_run = m_new;

    // ---- P -> wave-private LDS (row q=rl, stride 144 B) ----
    #pragma unroll
    for (int kb = 0; kb < 4; ++kb) {
      unsigned u0 = (unsigned)f2b(p[kb * 4 + 0]) | ((unsigned)f2b(p[kb * 4 + 1]) << 16);
      unsigned u1 = (unsigned)f2b(p[kb * 4 + 2]) | ((unsigned)f2b(p[kb * 4 + 3]) << 16);
      uint2 uu; uu.x = u0; uu.y = u1;
      *(uint2*)(pbase + kb * 32 + hi * 8) = uu;
    }

    // ---- rescale O by fac (redistribute to PV C-layout q = hi*4+r) ----
    #pragma unroll
    for (int r = 0; r < 4; ++r) {
      float fr = __shfl(fac, (l & 48) | (hi * 4 + r));
      oacc[0][r] *= fr; oacc[1][r] *= fr; oacc[2][r] *= fr; oacc[3][r] *= fr;
    }

    // ---- PV: O[q][d] += P @ V ----
    bf16x8 pa0 = *(const bf16x8*)(pbase + hi * 16);
    bf16x8 pa1 = *(const bf16x8*)(pbase + 64 + hi * 16);
    #pragma unroll
    for (int f = 0; f < 4; ++f) {
      int d = f * 16 + rl;
      unsigned char* vr = smem + 8192 + d * 128;
      bf16x8 v0 = *(const bf16x8*)(vr + (((hi) ^ (d & 7)) * 16));
      bf16x8 v1 = *(const bf16x8*)(vr + (((4 + hi) ^ (d & 7)) * 16));
      oacc[f] = MFMA16(pa0, v0, oacc[f]);
      oacc[f] = MFMA16(pa1, v1, oacc[f]);
    }
  }

  // ---- epilogue: normalize and store f32 ----
  float inv = 1.f / l_run;   // softmax layout (q = rl)
  #pragma unroll
  for (int r = 0; r < 4; ++r) {
    float ir = __shfl(inv, (l & 48) | (hi * 4 + r));
    int row = b * TT + t0w + hi * 4 + r;
    #pragma unroll
    for (int f = 0; f < 4; ++f)
      out[(size_t)row * HS + f * 16 + rl] = oacc[f][r] * ir;
  }
}

extern "C" void kernel_launch(void* const* d_in, const int* in_sizes, int n_in,
                              void* d_out, int out_size, void* d_ws, size_t ws_size,
                              hipStream_t stream) {
  // setup_inputs dict order: x, w_key, w_query, w_value
  const float* x  = (const float*)d_in[0];
  const float* wk = (const float*)d_in[1];
  const float* wq = (const float*)d_in[2];
  const float* wv = (const float*)d_in[3];
  float* out = (float*)d_out;

  unsigned short* wp    = (unsigned short*)d_ws;        // 196608 el = 384 KB
  unsigned short* q_ws  = wp + 196608;                  // 1 Mi el = 2 MB
  unsigned short* k_ws  = q_ws + (size_t)NROW * HS;     // 2 MB
  unsigned short* vt_ws = k_ws + (size_t)NROW * HS;     // 2 MB

  pack_w_kernel<<<192, 256, 0, stream>>>(wq, wk, wv, wp);
  proj_mfma_kernel<<<NROW / 64, 256, 0, stream>>>(x, wp, q_ws, k_ws, vt_ws);
  attn_mfma_kernel<<<BB * (TT / 64), 256, 0, stream>>>(q_ws, k_ws, vt_ws, out);
}

// Round 4
// 54.185 us; speedup vs baseline: 3.5303x; 2.4516x over previous
//
#include <hip/hip_runtime.h>
#include <math.h>

#define BB 4
#define TT 4096
#define CC 1024
#define HS 64
#define WIN 512
#define NROW (BB*TT)

typedef float f32x4 __attribute__((ext_vector_type(4)));
typedef short bf16x8 __attribute__((ext_vector_type(8)));

#define MFMA16(a, b, c) __builtin_amdgcn_mfma_f32_16x16x32_bf16((a), (b), (c), 0, 0, 0)

__device__ inline unsigned short f2b(float f) {
  union { float f; unsigned u; } v; v.f = f;
  unsigned r = v.u + 0x7FFFu + ((v.u >> 16) & 1u);   // round-nearest-even
  return (unsigned short)(r >> 16);
}

// ---------------- pack W into MFMA B-fragment order (bf16) ----------------
// wp flat index: ((kt*12 + nb)*64 + lane)*8 + j
// holds W[k = kt*32 + (lane>>4)*8 + j][n = nb*16 + (lane&15)],
// n: 0..63 = w_query, 64..127 = w_key, 128..191 = w_value
__global__ __launch_bounds__(256) void pack_w_kernel(
    const float* __restrict__ wq, const float* __restrict__ wk,
    const float* __restrict__ wv, unsigned short* __restrict__ wp)
{
  int t = blockIdx.x * 256 + threadIdx.x;   // 49152 threads
  int kg = t / 48;                          // 0..1023  (k index)
  int nq = t % 48;                          // 4-col group
  int n0 = nq * 4;
  int m  = n0 >> 6;
  int c  = n0 & 63;
  const float* w = (m == 0) ? wq : (m == 1) ? wk : wv;
  float4 v = *(const float4*)&w[(size_t)kg * HS + c];
  int kt = kg >> 5;
  int hi = (kg >> 3) & 3;
  int j  = kg & 7;
  float vals[4] = {v.x, v.y, v.z, v.w};
  #pragma unroll
  for (int i = 0; i < 4; ++i) {
    int n  = n0 + i;
    int nb = n >> 4;
    int rl = n & 15;
    int lane = hi * 16 + rl;
    wp[((size_t)(kt * 12 + nb) * 64 + lane) * 8 + j] = f2b(vals[i]);
  }
}

// ---------------- Projection via MFMA: [q|k|v] = x @ W ----------------
// grid 512 blocks x 256 threads (4 waves = 2 rowhalves x 2 colhalves).
// Wave = 16 rows x 96 cols (6 MFMA col-blocks). Register-pipelined, no LDS:
// x prefetched 4 kt deep, wp 2 kt deep.
__global__ __launch_bounds__(256) void proj_mfma_kernel(
    const float* __restrict__ x, const unsigned short* __restrict__ wp,
    unsigned short* __restrict__ q_ws, unsigned short* __restrict__ k_ws,
    unsigned short* __restrict__ vt_ws)
{
  const int tid = threadIdx.x;
  const int l   = tid & 63;
  const int wid = tid >> 6;
  const int rowhalf = wid >> 1;
  const int colhalf = wid & 1;
  const int r0  = blockIdx.x * 32 + rowhalf * 16;
  const int rl  = l & 15;
  const int hi  = l >> 4;
  const int nb0 = colhalf * 6;

  f32x4 acc[6];
  #pragma unroll
  for (int i = 0; i < 6; ++i) acc[i] = (f32x4){0.f, 0.f, 0.f, 0.f};

  const float* xrow = x + (size_t)(r0 + rl) * CC + hi * 8;
  const unsigned short* wpl = wp + (size_t)nb0 * 512 + l * 8;

#define LOADX(D0v, D1v, KTv) { D0v = *(const float4*)(xrow + (KTv) * 32); \
                               D1v = *(const float4*)(xrow + (KTv) * 32 + 4); }
#define LOADW(DSTv, KTv) { _Pragma("unroll") \
    for (int jj = 0; jj < 6; ++jj) DSTv[jj] = *(const bf16x8*)(wpl + (size_t)(KTv) * 6144 + jj * 512); }
#define COMPUTE(A0v, A1v, WFv) { bf16x8 af; \
    af[0] = (short)f2b((A0v).x); af[1] = (short)f2b((A0v).y); \
    af[2] = (short)f2b((A0v).z); af[3] = (short)f2b((A0v).w); \
    af[4] = (short)f2b((A1v).x); af[5] = (short)f2b((A1v).y); \
    af[6] = (short)f2b((A1v).z); af[7] = (short)f2b((A1v).w); \
    _Pragma("unroll") \
    for (int jj = 0; jj < 6; ++jj) acc[jj] = MFMA16(af, WFv[jj], acc[jj]); }

  float4 xA0, xA1, xB0, xB1, xC0, xC1, xD0, xD1;
  bf16x8 wP[6], wQ[6];

  LOADX(xA0, xA1, 0) LOADX(xB0, xB1, 1) LOADX(xC0, xC1, 2) LOADX(xD0, xD1, 3)
  LOADW(wP, 0) LOADW(wQ, 1)

  for (int kt = 0; kt < 32; kt += 4) {
    COMPUTE(xA0, xA1, wP)
    if (kt + 4 < 32) { LOADX(xA0, xA1, kt + 4) }
    if (kt + 2 < 32) { LOADW(wP, kt + 2) }
    COMPUTE(xB0, xB1, wQ)
    if (kt + 5 < 32) { LOADX(xB0, xB1, kt + 5) }
    if (kt + 3 < 32) { LOADW(wQ, kt + 3) }
    COMPUTE(xC0, xC1, wP)
    if (kt + 6 < 32) { LOADX(xC0, xC1, kt + 6) }
    if (kt + 4 < 32) { LOADW(wP, kt + 4) }
    COMPUTE(xD0, xD1, wQ)
    if (kt + 7 < 32) { LOADX(xD0, xD1, kt + 7) }
    if (kt + 5 < 32) { LOADW(wQ, kt + 5) }
  }
#undef LOADX
#undef LOADW
#undef COMPUTE

  // store: nb = nb0 + j; nb 0..3 -> q, 4..7 -> k, 8..11 -> v (transposed)
  #pragma unroll
  for (int j = 0; j < 6; ++j) {
    int nb = nb0 + j;
    if (nb < 8) {
      unsigned short* dst = (nb < 4) ? q_ws : k_ws;
      int c = (nb & 3) * 16 + rl;
      #pragma unroll
      for (int r = 0; r < 4; ++r) {
        int row = r0 + hi * 4 + r;
        dst[(size_t)row * HS + c] = f2b(acc[j][r]);
      }
    } else {
      int ch   = r0 >> 6;
      int key0 = (r0 & 63) + hi * 4;
      int d = (nb - 8) * 16 + rl;
      unsigned u0 = (unsigned)f2b(acc[j][0]) | ((unsigned)f2b(acc[j][1]) << 16);
      unsigned u1 = (unsigned)f2b(acc[j][2]) | ((unsigned)f2b(acc[j][3]) << 16);
      uint2 uu; uu.x = u0; uu.y = u1;
      *(uint2*)(vt_ws + (size_t)ch * 4096 + d * 64 + key0) = uu;
    }
  }
}

// ---------------- Sliding-window flash attention via MFMA ----------------
// grid 256 blocks (b, 64-q tile) x 256 threads (4 waves, 16 q-rows each).
// Swapped QK^T (S^T = K @ Q^T) -> softmax lane-local; P via wave-private LDS;
// PV with V^T staged swizzled.
__global__ __launch_bounds__(256) void attn_mfma_kernel(
    const unsigned short* __restrict__ q_ws, const unsigned short* __restrict__ k_ws,
    const unsigned short* __restrict__ vt_ws, float* __restrict__ out)
{
  __shared__ uint4 smem4[1600];                 // 25600 B
  unsigned char* smem = (unsigned char*)smem4;  // K:[0,8K) Vt:[8K,16K) P:16K+

  const int tid = threadIdx.x;
  const int l   = tid & 63;
  const int wid = tid >> 6;
  const int rl  = l & 15;
  const int hi  = l >> 4;
  const int b   = blockIdx.x >> 6;
  const int qt  = blockIdx.x & 63;
  const int t0  = qt * 64;
  const int t0w = t0 + wid * 16;

  // Q B-fragments (held in registers): lane = q row t0w+rl, d = hi*8+j (+32)
  const unsigned short* qrow = q_ws + (size_t)(b * TT + t0w + rl) * HS;
  bf16x8 qb0 = *(const bf16x8*)(qrow + hi * 8);
  bf16x8 qb1 = *(const bf16x8*)(qrow + 32 + hi * 8);

  f32x4 oacc[4];
  #pragma unroll
  for (int i = 0; i < 4; ++i) oacc[i] = (f32x4){0.f, 0.f, 0.f, 0.f};
  float m_run = -INFINITY, l_run = 0.f;

  int s_lo = t0 - WIN; if (s_lo < 0) s_lo = 0;
  unsigned char* pbase = smem + 16384 + wid * 2304 + rl * 144;

  for (int sc = s_lo; sc < t0 + 64; sc += 64) {
    __syncthreads();
    // ---- stage K and Vt chunk (64x64 bf16 each), XOR-swizzled rows ----
    {
      const unsigned short* kg = k_ws + (size_t)(b * TT + sc) * HS;
      const unsigned short* vg = vt_ws + (size_t)((b * TT + sc) >> 6) * 4096;
      #pragma unroll
      for (int i = 0; i < 2; ++i) {
        int idx = tid + i * 256;
        int row = idx >> 3;
        int c16 = idx & 7;
        uint4 kv = *(const uint4*)(kg + row * 64 + c16 * 8);
        uint4 vv = *(const uint4*)(vg + row * 64 + c16 * 8);
        *(uint4*)(smem + row * 128 + ((c16 ^ (row & 7)) * 16)) = kv;
        *(uint4*)(smem + 8192 + row * 128 + ((c16 ^ (row & 7)) * 16)) = vv;
      }
    }
    __syncthreads();

    // ---- S^T = K @ Q^T : 4 key-block fragments ----
    f32x4 sacc[4];
    #pragma unroll
    for (int i = 0; i < 4; ++i) sacc[i] = (f32x4){0.f, 0.f, 0.f, 0.f};
    #pragma unroll
    for (int kb = 0; kb < 4; ++kb) {
      int row = kb * 16 + rl;
      unsigned char* kr = smem + row * 128;
      bf16x8 k0 = *(const bf16x8*)(kr + (((hi) ^ (row & 7)) * 16));
      bf16x8 k1 = *(const bf16x8*)(kr + (((4 + hi) ^ (row & 7)) * 16));
      sacc[kb] = MFMA16(k0, qb0, sacc[kb]);
      sacc[kb] = MFMA16(k1, qb1, sacc[kb]);
    }

    // ---- mask + scale + online softmax (lane owns one q = t0w+rl) ----
    const int tg = t0w + rl;
    float p[16];
    float tm = -INFINITY;
    bool full = (sc + 63 <= t0w) && (sc >= t0w - 496);
    #pragma unroll
    for (int kb = 0; kb < 4; ++kb)
      #pragma unroll
      for (int r = 0; r < 4; ++r) {
        float v = sacc[kb][r] * 0.125f;
        if (!full) {
          int key = sc + kb * 16 + hi * 4 + r;
          int diff = tg - key;
          v = (diff >= 0 && diff < WIN) ? v : -INFINITY;
        }
        p[kb * 4 + r] = v;
        tm = fmaxf(tm, v);
      }
    tm = fmaxf(tm, __shfl_xor(tm, 16));
    tm = fmaxf(tm, __shfl_xor(tm, 32));
    float m_new = fmaxf(m_run, tm);
    float fac  = (m_new == -INFINITY) ? 1.f : __expf(m_run - m_new);
    float msub = (m_new == -INFINITY) ? 0.f : m_new;
    float lsum = 0.f;
    #pragma unroll
    for (int i = 0; i < 16; ++i) { p[i] = __expf(p[i] - msub); lsum += p[i]; }
    lsum += __shfl_xor(lsum, 16);
    lsum += __shfl_xor(lsum, 32);
    l_run = l_run * fac + lsum;
    m_run = m_new;

    // ---- P -> wave-private LDS (row q=rl, stride 144 B) ----
    #pragma unroll
    for (int kb = 0; kb < 4; ++kb) {
      unsigned u0 = (unsigned)f2b(p[kb * 4 + 0]) | ((unsigned)f2b(p[kb * 4 + 1]) << 16);
      unsigned u1 = (unsigned)f2b(p[kb * 4 + 2]) | ((unsigned)f2b(p[kb * 4 + 3]) << 16);
      uint2 uu; uu.x = u0; uu.y = u1;
      *(uint2*)(pbase + kb * 32 + hi * 8) = uu;
    }

    // ---- rescale O by fac (redistribute to PV C-layout q = hi*4+r) ----
    #pragma unroll
    for (int r = 0; r < 4; ++r) {
      float fr = __shfl(fac, (l & 48) | (hi * 4 + r));
      oacc[0][r] *= fr; oacc[1][r] *= fr; oacc[2][r] *= fr; oacc[3][r] *= fr;
    }

    // ---- PV: O[q][d] += P @ V ----
    bf16x8 pa0 = *(const bf16x8*)(pbase + hi * 16);
    bf16x8 pa1 = *(const bf16x8*)(pbase + 64 + hi * 16);
    #pragma unroll
    for (int f = 0; f < 4; ++f) {
      int d = f * 16 + rl;
      unsigned char* vr = smem + 8192 + d * 128;
      bf16x8 v0 = *(const bf16x8*)(vr + (((hi) ^ (d & 7)) * 16));
      bf16x8 v1 = *(const bf16x8*)(vr + (((4 + hi) ^ (d & 7)) * 16));
      oacc[f] = MFMA16(pa0, v0, oacc[f]);
      oacc[f] = MFMA16(pa1, v1, oacc[f]);
    }
  }

  // ---- epilogue: normalize and store f32 ----
  float inv = 1.f / l_run;   // softmax layout (q = rl)
  #pragma unroll
  for (int r = 0; r < 4; ++r) {
    float ir = __shfl(inv, (l & 48) | (hi * 4 + r));
    int row = b * TT + t0w + hi * 4 + r;
    #pragma unroll
    for (int f = 0; f < 4; ++f)
      out[(size_t)row * HS + f * 16 + rl] = oacc[f][r] * ir;
  }
}

extern "C" void kernel_launch(void* const* d_in, const int* in_sizes, int n_in,
                              void* d_out, int out_size, void* d_ws, size_t ws_size,
                              hipStream_t stream) {
  // setup_inputs dict order: x, w_key, w_query, w_value
  const float* x  = (const float*)d_in[0];
  const float* wk = (const float*)d_in[1];
  const float* wq = (const float*)d_in[2];
  const float* wv = (const float*)d_in[3];
  float* out = (float*)d_out;

  unsigned short* wp    = (unsigned short*)d_ws;        // 196608 el = 384 KB
  unsigned short* q_ws  = wp + 196608;                  // 2 MB
  unsigned short* k_ws  = q_ws + (size_t)NROW * HS;     // 2 MB
  unsigned short* vt_ws = k_ws + (size_t)NROW * HS;     // 2 MB

  pack_w_kernel<<<192, 256, 0, stream>>>(wq, wk, wv, wp);
  proj_mfma_kernel<<<NROW / 32, 256, 0, stream>>>(x, wp, q_ws, k_ws, vt_ws);
  attn_mfma_kernel<<<BB * (TT / 64), 256, 0, stream>>>(q_ws, k_ws, vt_ws, out);
}